// Round 19
// baseline (411.337 us; speedup 1.0000x reference)
//
#include <hip/hip_runtime.h>
#include <hip/hip_bf16.h>
#include <stdint.h>

// AWQ GEMM: out[2048,11008](f32) = x[2048,4096](f32,f16-valued) @ dequant4(...) + bias
// Round 19: hoist dequant OUT of the GEMM. r14/r16/r18 (four schedules) all tie at
// 238us / MfmaUtil 27% -> the shared cost is the in-loop B-dequant (VALU chain +
// 64 scattered ds_write_b32/iter, redundant 8x per weight across mtile-blocks).
//  K1: X f32->f16, MFMA-fragment order (r16 layout) -> Xsw.
//  K2: W dequant ONCE -> Wsw (f16), stored as the EXACT pre-swizzled B-LDS image
//      (byte-identical to stage_B's output; read_b unchanged).
//  K3: GEMM with zero staging VALU: A global->reg prefetched (r16 machinery),
//      B via 2x global_load_lds per iter from Wsw, 1 barrier/iter.
// Tiers: ws >= 107MB -> K1+K2+K3 ; ws >= 16MB -> r16 path ; else r12 fallback.

constexpr int TOKENS = 2048;
constexpr int IN_F   = 4096;
constexpr int OUT_F  = 11008;
constexpr int PCOLS  = OUT_F / 8;   // 1376
constexpr int BM = 256, BN = 128, BK = 64;
constexpr int NKT    = IN_F / BK;   // 64
constexpr int NTILES = OUT_F / BN;  // 86
constexpr int BBYTES = BN * BK * 2; // 16384 per B buffer
constexpr size_t XSW_BYTES = (size_t)TOKENS * IN_F * 2;          // 16,777,216
constexpr size_t WSW_BYTES = (size_t)IN_F * OUT_F * 2;           // 90,177,536
constexpr size_t WS_FULL   = XSW_BYTES + WSW_BYTES;              // 106,954,752

typedef _Float16 h2 __attribute__((ext_vector_type(2)));
typedef _Float16 h8 __attribute__((ext_vector_type(8)));
typedef float f32x4  __attribute__((ext_vector_type(4)));

__device__ __forceinline__ h2 pkh2(float a, float b) {
    return __builtin_bit_cast(h2, __builtin_amdgcn_cvt_pkrtz(a, b));
}
__device__ __forceinline__ unsigned int pk2(float a, float b) {
    return __builtin_bit_cast(unsigned int, __builtin_amdgcn_cvt_pkrtz(a, b));
}
__device__ __forceinline__ void gld_lds16(const void* g, void* l) {
    __builtin_amdgcn_global_load_lds(
        (const __attribute__((address_space(1))) void*)g,
        (__attribute__((address_space(3))) void*)l,
        16, 0, 0);
}

__constant__ int SHC[8] = {0, 16, 4, 20, 8, 24, 12, 28}; // shift of logical nibble j

// ---------------- K1: convert X into fragment-ordered f16 ----------------
__global__ __launch_bounds__(256)
void x_convert_kernel(const float* __restrict__ X, unsigned short* __restrict__ Xsw)
{
    // g = ((((mt*64 + kt)*2 + ks)*4 + wm)*4 + mi)*64 + lane
    const int g    = blockIdx.x * 256 + threadIdx.x;   // 0 .. 2^20-1
    const int lane = g & 63;
    const int mi   = (g >> 6) & 3;
    const int wm   = (g >> 8) & 3;
    const int ks   = (g >> 10) & 1;
    const int kt   = (g >> 11) & 63;
    const int mt   = g >> 17;
    const int row  = mt * 256 + wm * 64 + mi * 16 + (lane & 15);
    const int kcol = kt * 64 + (ks * 4 + (lane >> 4)) * 8;
    const float* src = X + (size_t)row * IN_F + kcol;
    float4 v0 = *(const float4*)(src);
    float4 v1 = *(const float4*)(src + 4);
    uint4 u;
    u.x = pk2(v0.x, v0.y);
    u.y = pk2(v0.z, v0.w);
    u.z = pk2(v1.x, v1.y);
    u.w = pk2(v1.z, v1.w);
    *(uint4*)(Xsw + (size_t)g * 8) = u;
}

// ---------------- K2: dequant W once into pre-swizzled B-LDS image ----------------
// Wsw chunk for (nt, kt) is 16384 B = the B LDS buffer image:
//   col n (0..127) * 128B; 16B slot s holds k-octet o = s^(n&7)^((n>>3)&7),
//   i.e. f16 weights W[kt*64 + o*8 .. +8][nt*128 + n], increasing k.
__global__ __launch_bounds__(256)
void w_dequant_kernel(const int*   __restrict__ QW,
                      const int*   __restrict__ QZ,
                      const float* __restrict__ S,
                      unsigned short* __restrict__ Wsw)
{
    const int id = blockIdx.x * 256 + threadIdx.x;     // one 16B chunk each
    const int nt  = id >> 16;                          // 64*1024 chunks per ntile
    const int rem = id & 65535;
    const int kt  = rem >> 10;
    const int c   = rem & 1023;
    const int n   = c >> 3;
    const int slot = c & 7;
    const int o   = slot ^ (n & 7) ^ ((n >> 3) & 7);   // involution
    const int pcol = n >> 3;
    const int jsh  = SHC[n & 7];
    const int g    = kt >> 1;                          // group (gs=128)
    const int qcol = nt * 16 + pcol;

    const unsigned int zraw = ((const unsigned int*)QZ)[(size_t)g * PCOLS + qcol];
    const float s = S[(size_t)g * OUT_F + nt * 128 + n];
    const h2 spk = pkh2(s, s);
    const float zb = 1024.0f + (float)((zraw >> jsh) & 15u);
    const h2 zpk = pkh2(zb, zb);

    const int krow0 = kt * 64 + o * 8;
    unsigned int q[8];
#pragma unroll
    for (int kk = 0; kk < 8; ++kk) {
        unsigned int raw = (unsigned int)QW[(size_t)(krow0 + kk) * PCOLS + qcol];
        q[kk] = ((raw >> jsh) & 15u) | 0x6400u;        // f16 (1024+q), exact
    }
    uint4 u;
    unsigned int* up = (unsigned int*)&u;
#pragma unroll
    for (int p = 0; p < 4; ++p) {
        unsigned int pair = q[2 * p] | (q[2 * p + 1] << 16);
        h2 wv = (__builtin_bit_cast(h2, pair) - zpk) * spk;   // exact sub, 1 rounding
        up[p] = __builtin_bit_cast(unsigned int, wv);
    }
    *(uint4*)(Wsw + (size_t)id * 8) = u;
}

// ---------------- K3: pure GEMM (A reg-prefetch, B DMA from Wsw) ----------------
__global__ __launch_bounds__(512, 2)
void awq_gemm_full_kernel(const unsigned short* __restrict__ Xsw,
                          const unsigned short* __restrict__ Wsw,
                          const float* __restrict__ BIAS,
                          float*       __restrict__ O)
{
    // LDS: B buf b at b*16384 (pre-swizzled image, loaded linearly by DMA)
    __shared__ alignas(16) unsigned char smem[2 * BBYTES];  // 32 KB

    const int t    = threadIdx.x;
    const int lane = t & 63;
    const int w    = t >> 6;      // 0..7
    const int wm   = w >> 1;      // 0..3 (row block of 64)
    const int wn   = w & 1;       // 0..1 (col block of 64)
    const int l15 = lane & 15, l45 = lane >> 4, l7 = lane & 7, l3 = (lane >> 3) & 1;

    // XCD mapping: XCD x (= bid&7) owns mtile x; sweeps all 86 ntiles. 688 = 8*86.
    const int bid   = blockIdx.x;
    const int mtile = bid & 7;
    const int ntile = bid >> 3;
    const int m0 = mtile * BM;
    const int n0 = ntile * BN;

    // ---- A fragments: direct global loads from fragment-ordered Xsw (r16 proven) ----
    const h8* Afrag = (const h8*)Xsw;
    auto load_afull = [&](h8 (&a)[2][4], int kt) {
#pragma unroll
        for (int ks = 0; ks < 2; ++ks) {
            const size_t base = ((((size_t)mtile * 64 + kt) * 2 + ks) * 4 + wm) * 4;
#pragma unroll
            for (int mi = 0; mi < 4; ++mi)
                a[ks][mi] = Afrag[(base + mi) * 64 + lane];
        }
    };

    // ---- B staging: 2 DMA issues per iter, 16KB tile, linear ----
    const unsigned char* WswB = (const unsigned char*)Wsw;
    auto stage_B_dma = [&](int buf, int kt) {
        unsigned char* bb = smem + buf * BBYTES;
        const unsigned char* src = WswB + ((size_t)ntile * 64 + kt) * 16384;
#pragma unroll
        for (int i = 0; i < 2; ++i)
            gld_lds16(src + (i * 512 + t) * 16, bb + i * 8192 + w * 1024);
    };

    f32x4 acc[4][4];
#pragma unroll
    for (int mi = 0; mi < 4; ++mi)
#pragma unroll
        for (int ni = 0; ni < 4; ++ni)
            acc[mi][ni] = f32x4{0.f, 0.f, 0.f, 0.f};

    auto compute_tile = [&](int buf, const h8 (&a)[2][4]) {
        const unsigned char* bb = smem + buf * BBYTES;
#pragma unroll
        for (int ks = 0; ks < 2; ++ks) {
            h8 bf[4];
#pragma unroll
            for (int ni = 0; ni < 4; ++ni) {
                int off = (wn * 64 + ni * 16 + l15) * 128
                        + ((((ks * 4 + l45) ^ l7 ^ l3) ^ (2 * ni)) * 16); // n&7==l7
                bf[ni] = *(const h8*)(bb + off);
            }
#pragma unroll
            for (int mi = 0; mi < 4; ++mi)
#pragma unroll
                for (int ni = 0; ni < 4; ++ni)
                    acc[mi][ni] = __builtin_amdgcn_mfma_f32_16x16x32_f16(
                        a[ks][mi], bf[ni], acc[mi][ni], 0, 0, 0);
        }
    };

    h8 aA[2][4], aB[2][4];

    // ---- prologue: A frags kt=0 -> aA ; B tile 0 -> buf 0 ----
    load_afull(aA, 0);
    stage_B_dma(0, 0);
    __syncthreads();   // drains DMA

    // ---- one K-iteration: consume aC, prefetch aN + next B tile ----
    auto K_ITER = [&](int kt, h8 (&aC)[2][4], h8 (&aN)[2][4]) {
        const int cur = kt & 1;
        if (kt + 1 < NKT) {
            stage_B_dma(cur ^ 1, kt + 1);      // async DMA, drains at iter-end barrier
            load_afull(aN, kt + 1);            // global->reg, full-iter latency cover
        }
        compute_tile(cur, aC);
        __syncthreads();
    };

    // ---- main loop: static even/odd A reg-set alternation (rule #20) ----
#pragma unroll 1
    for (int kt = 0; kt < NKT; kt += 2) {
        K_ITER(kt,     aA, aB);
        K_ITER(kt + 1, aB, aA);
    }

    // ---- epilogue: bias + f32 store (C/D: col=lane&15, row=(lane>>4)*4+reg) ----
    const int orow0 = m0 + wm * 64 + l45 * 4;
    const int ocol0 = n0 + wn * 64 + l15;
    float bv[4];
#pragma unroll
    for (int ni = 0; ni < 4; ++ni)
        bv[ni] = BIAS[ocol0 + ni * 16];
#pragma unroll
    for (int mi = 0; mi < 4; ++mi)
#pragma unroll
        for (int ni = 0; ni < 4; ++ni)
#pragma unroll
            for (int r = 0; r < 4; ++r) {
                int row = orow0 + mi * 16 + r;
                int col = ocol0 + ni * 16;
                O[(size_t)row * OUT_F + col] = acc[mi][ni][r] + bv[ni];
            }
}

// ---------------- mid tier: r16 kernel verbatim (A reg, in-loop dequant) ----------------
__global__ __launch_bounds__(512, 2)
void awq_gemm_reg_kernel(const unsigned short* __restrict__ Xsw,
                         const int*   __restrict__ QW,
                         const int*   __restrict__ QZ,
                         const float* __restrict__ S,
                         const float* __restrict__ BIAS,
                         float*       __restrict__ O)
{
    __shared__ alignas(16) unsigned char smem[2 * BBYTES];

    const int t    = threadIdx.x;
    const int lane = t & 63;
    const int w    = t >> 6;
    const int wm   = w >> 1;
    const int wn   = w & 1;
    const int l15 = lane & 15, l45 = lane >> 4, l7 = lane & 7, l3 = (lane >> 3) & 1;

    const int bid   = blockIdx.x;
    const int mtile = bid & 7;
    const int ntile = bid >> 3;
    const int m0 = mtile * BM;
    const int n0 = ntile * BN;
    const int P0 = n0 >> 3;

    const h8* Afrag = (const h8*)Xsw;
    auto load_afull = [&](h8 (&a)[2][4], int kt) {
#pragma unroll
        for (int ks = 0; ks < 2; ++ks) {
            const size_t base = ((((size_t)mtile * 64 + kt) * 2 + ks) * 4 + wm) * 4;
#pragma unroll
            for (int mi = 0; mi < 4; ++mi)
                a[ks][mi] = Afrag[(base + mi) * 64 + lane];
        }
    };

    const int pcol = t & 15;
    const int kd   = t >> 4;
    const int pc7  = pcol & 7;
    const int ob   = kd >> 2;
    const int sub  = (kd & 3) * 4;
    const int* qwb = QW + (size_t)(2 * kd) * PCOLS + P0 + pcol;
    const unsigned int* qzc = (const unsigned int*)QZ + P0 + pcol;
    const float* scol = S + n0 + pcol * 8;

    constexpr int SH[8]  = {0, 16, 4, 20, 8, 24, 12, 28};
    constexpr int JLO[4] = {0, 4, 1, 5};

    h2 spk[8], zpk[8];
    unsigned int zraw_n; float4 sv0, sv1;
    unsigned int raw0, raw1;

    auto load_group = [&](int g) {
        zraw_n = qzc[(size_t)g * PCOLS];
        sv0 = *(const float4*)(scol + (size_t)g * OUT_F);
        sv1 = *(const float4*)(scol + (size_t)g * OUT_F + 4);
    };
    auto compute_group = [&]() {
        const float sf[8] = {sv0.x, sv0.y, sv0.z, sv0.w, sv1.x, sv1.y, sv1.z, sv1.w};
#pragma unroll
        for (int j = 0; j < 8; ++j) {
            float zb = 1024.0f + (float)((zraw_n >> SH[j]) & 15u);
            spk[j] = pkh2(sf[j], sf[j]);
            zpk[j] = pkh2(zb, zb);
        }
    };
    auto load_raws = [&](int kt) {
        const size_t off = (size_t)kt * BK * PCOLS;
        raw0 = (unsigned int)qwb[off];
        raw1 = (unsigned int)qwb[off + PCOLS];
    };
    auto stage_B = [&](int buf) {
        unsigned char* bb = smem + buf * BBYTES;
#pragma unroll
        for (int b = 0; b < 4; ++b) {
            const int jl = JLO[b], jh = jl + 2;
            unsigned int d  = __builtin_amdgcn_perm(raw1, raw0,
                                 (unsigned int)(((4 + b) << 16) | b));
            unsigned int lo = (d & 0x000F000Fu) | 0x64006400u;
            unsigned int hi = ((d >> 4) & 0x000F000Fu) | 0x64006400u;
            h2 wl = (__builtin_bit_cast(h2, lo) - zpk[jl]) * spk[jl];
            h2 wh = (__builtin_bit_cast(h2, hi) - zpk[jh]) * spk[jh];
            const int nl = pcol * 8 + jl, nh = pcol * 8 + jh;
            *(unsigned int*)(bb + nl * 128 + ((ob ^ jl ^ pc7) * 16) + sub) =
                __builtin_bit_cast(unsigned int, wl);
            *(unsigned int*)(bb + nh * 128 + ((ob ^ jh ^ pc7) * 16) + sub) =
                __builtin_bit_cast(unsigned int, wh);
        }
    };

    f32x4 acc[4][4];
#pragma unroll
    for (int mi = 0; mi < 4; ++mi)
#pragma unroll
        for (int ni = 0; ni < 4; ++ni)
            acc[mi][ni] = f32x4{0.f, 0.f, 0.f, 0.f};

    auto compute_tile = [&](int buf, const h8 (&a)[2][4]) {
        const unsigned char* bb = smem + buf * BBYTES;
#pragma unroll
        for (int ks = 0; ks < 2; ++ks) {
            h8 bf[4];
#pragma unroll
            for (int ni = 0; ni < 4; ++ni) {
                int off = (wn * 64 + ni * 16 + l15) * 128
                        + ((((ks * 4 + l45) ^ l7 ^ l3) ^ (2 * ni)) * 16);
                bf[ni] = *(const h8*)(bb + off);
            }
#pragma unroll
            for (int mi = 0; mi < 4; ++mi)
#pragma unroll
                for (int ni = 0; ni < 4; ++ni)
                    acc[mi][ni] = __builtin_amdgcn_mfma_f32_16x16x32_f16(
                        a[ks][mi], bf[ni], acc[mi][ni], 0, 0, 0);
        }
    };

    h8 aA[2][4], aB[2][4];

    load_afull(aA, 0);
    load_raws(0);
    load_group(0);
    compute_group();
    stage_B(0);
    __syncthreads();

    auto K_ITER = [&](int kt, h8 (&aC)[2][4], h8 (&aN)[2][4]) {
        const int cur = kt & 1;
        if (kt + 1 < NKT) {
            load_afull(aN, kt + 1);
            load_raws(kt + 1);
            if (((kt + 1) & 1) == 0) load_group((kt + 1) >> 1);
        }
        compute_tile(cur, aC);
        if (kt + 1 < NKT) {
            if (((kt + 1) & 1) == 0) compute_group();
            stage_B(cur ^ 1);
        }
        __syncthreads();
    };

#pragma unroll 1
    for (int kt = 0; kt < NKT; kt += 2) {
        K_ITER(kt,     aA, aB);
        K_ITER(kt + 1, aB, aA);
    }

    const int orow0 = m0 + wm * 64 + l45 * 4;
    const int ocol0 = n0 + wn * 64 + l15;
    float bv[4];
#pragma unroll
    for (int ni = 0; ni < 4; ++ni)
        bv[ni] = BIAS[ocol0 + ni * 16];
#pragma unroll
    for (int mi = 0; mi < 4; ++mi)
#pragma unroll
        for (int ni = 0; ni < 4; ++ni)
#pragma unroll
            for (int r = 0; r < 4; ++r) {
                int row = orow0 + mi * 16 + r;
                int col = ocol0 + ni * 16;
                O[(size_t)row * OUT_F + col] = acc[mi][ni][r] + bv[ni];
            }
}

// ---------------- fallback: r12 kernel (no usable ws) ----------------
constexpr int ABYTES_FB = BM * BK * 2; // 32768

__global__ __launch_bounds__(512, 2)
void awq_gemm_fb_kernel(const float* __restrict__ X,
                        const int*   __restrict__ QW,
                        const int*   __restrict__ QZ,
                        const float* __restrict__ S,
                        const float* __restrict__ BIAS,
                        float*       __restrict__ O)
{
    __shared__ alignas(16) unsigned char smem[ABYTES_FB + 2 * BBYTES];

    const int t    = threadIdx.x;
    const int lane = t & 63;
    const int w    = t >> 6;
    const int wm   = w >> 1;
    const int wn   = w & 1;
    const int l15 = lane & 15, l45 = lane >> 4, l7 = lane & 7, l3 = (lane >> 3) & 1;

    const int bid   = blockIdx.x;
    const int mtile = bid & 7;
    const int ntile = bid >> 3;
    const int m0 = mtile * BM;
    const int n0 = ntile * BN;
    const int P0 = n0 >> 3;

    const int arow = t >> 3;
    const int aoct = t & 7;
    const int aphys = aoct ^ (arow & 7);
    const float* Xb = X + (size_t)(m0 + arow) * IN_F + aoct * 8;

    float4 areg[4][2];
    auto load_A = [&](int kt) {
#pragma unroll
        for (int i = 0; i < 4; ++i) {
            const float* p = Xb + (size_t)i * 64 * IN_F + kt * BK;
            areg[i][0] = *(const float4*)(p);
            areg[i][1] = *(const float4*)(p + 4);
        }
    };
    auto write_A = [&]() {
        unsigned char* ab = smem;
#pragma unroll
        for (int i = 0; i < 4; ++i) {
            uint4 v;
            v.x = pk2(areg[i][0].x, areg[i][0].y);
            v.y = pk2(areg[i][0].z, areg[i][0].w);
            v.z = pk2(areg[i][1].x, areg[i][1].y);
            v.w = pk2(areg[i][1].z, areg[i][1].w);
            *(uint4*)(ab + (i * 64 + arow) * 128 + aphys * 16) = v;
        }
    };

    const int pcol = t & 15;
    const int kd   = t >> 4;
    const int pc7  = pcol & 7;
    const int ob   = kd >> 2;
    const int sub  = (kd & 3) * 4;
    const int* qwb = QW + (size_t)(2 * kd) * PCOLS + P0 + pcol;
    const unsigned int* qzc = (const unsigned int*)QZ + P0 + pcol;
    const float* scol = S + n0 + pcol * 8;

    constexpr int SH[8]  = {0, 16, 4, 20, 8, 24, 12, 28};
    constexpr int JLO[4] = {0, 4, 1, 5};

    h2 spk[8], zpk[8];
    unsigned int zraw_n; float4 sv0, sv1;
    unsigned int raw0, raw1;

    auto load_group = [&](int g) {
        zraw_n = qzc[(size_t)g * PCOLS];
        sv0 = *(const float4*)(scol + (size_t)g * OUT_F);
        sv1 = *(const float4*)(scol + (size_t)g * OUT_F + 4);
    };
    auto compute_group = [&]() {
        const float sf[8] = {sv0.x, sv0.y, sv0.z, sv0.w, sv1.x, sv1.y, sv1.z, sv1.w};
#pragma unroll
        for (int j = 0; j < 8; ++j) {
            float zb = 1024.0f + (float)((zraw_n >> SH[j]) & 15u);
            spk[j] = pkh2(sf[j], sf[j]);
            zpk[j] = pkh2(zb, zb);
        }
    };
    auto load_raws = [&](int kt) {
        const size_t off = (size_t)kt * BK * PCOLS;
        raw0 = (unsigned int)qwb[off];
        raw1 = (unsigned int)qwb[off + PCOLS];
    };
    auto stage_B = [&](int buf) {
        unsigned char* bb = smem + ABYTES_FB + buf * BBYTES;
#pragma unroll
        for (int b = 0; b < 4; ++b) {
            const int jl = JLO[b], jh = jl + 2;
            unsigned int d  = __builtin_amdgcn_perm(raw1, raw0,
                                 (unsigned int)(((4 + b) << 16) | b));
            unsigned int lo = (d & 0x000F000Fu) | 0x64006400u;
            unsigned int hi = ((d >> 4) & 0x000F000Fu) | 0x64006400u;
            h2 wl = (__builtin_bit_cast(h2, lo) - zpk[jl]) * spk[jl];
            h2 wh = (__builtin_bit_cast(h2, hi) - zpk[jh]) * spk[jh];
            const int nl = pcol * 8 + jl, nh = pcol * 8 + jh;
            *(unsigned int*)(bb + nl * 128 + ((ob ^ jl ^ pc7) * 16) + sub) =
                __builtin_bit_cast(unsigned int, wl);
            *(unsigned int*)(bb + nh * 128 + ((ob ^ jh ^ pc7) * 16) + sub) =
                __builtin_bit_cast(unsigned int, wh);
        }
    };

    f32x4 acc[4][4];
#pragma unroll
    for (int mi = 0; mi < 4; ++mi)
#pragma unroll
        for (int ni = 0; ni < 4; ++ni)
            acc[mi][ni] = f32x4{0.f, 0.f, 0.f, 0.f};

    auto compute_tile = [&](int buf) {
        const unsigned char* ab = smem;
        const unsigned char* bb = smem + ABYTES_FB + buf * BBYTES;
#pragma unroll
        for (int ks = 0; ks < 2; ++ks) {
            h8 a[4], bf[4];
#pragma unroll
            for (int mi = 0; mi < 4; ++mi) {
                int off = (wm * 64 + mi * 16 + l15) * 128
                        + (((ks * 4 + l45) ^ l7) * 16);
                a[mi] = *(const h8*)(ab + off);
            }
#pragma unroll
            for (int ni = 0; ni < 4; ++ni) {
                int off = (wn * 64 + ni * 16 + l15) * 128
                        + ((((ks * 4 + l45) ^ l7 ^ l3) ^ (2 * ni)) * 16);
                bf[ni] = *(const h8*)(bb + off);
            }
#pragma unroll
            for (int mi = 0; mi < 4; ++mi)
#pragma unroll
                for (int ni = 0; ni < 4; ++ni)
                    acc[mi][ni] = __builtin_amdgcn_mfma_f32_16x16x32_f16(
                        a[mi], bf[ni], acc[mi][ni], 0, 0, 0);
        }
    };

    load_A(0);
    load_raws(0);
    load_group(0);
    compute_group();
    write_A();
    stage_B(0);
    __syncthreads();

#pragma unroll 2
    for (int kt = 0; kt < NKT; ++kt) {
        const int cur = kt & 1;
        if (kt + 1 < NKT) {
            load_A(kt + 1);
            load_raws(kt + 1);
            if (((kt + 1) & 1) == 0) load_group((kt + 1) >> 1);
        }
        compute_tile(cur);
        if (kt + 1 < NKT) {
            if (((kt + 1) & 1) == 0) compute_group();
            stage_B(cur ^ 1);
        }
        __syncthreads();
        if (kt + 1 < NKT) write_A();
        __syncthreads();
    }

    const int orow0 = m0 + wm * 64 + l45 * 4;
    const int ocol0 = n0 + wn * 64 + l15;
    float bv[4];
#pragma unroll
    for (int ni = 0; ni < 4; ++ni)
        bv[ni] = BIAS[ocol0 + ni * 16];
#pragma unroll
    for (int mi = 0; mi < 4; ++mi)
#pragma unroll
        for (int ni = 0; ni < 4; ++ni)
#pragma unroll
            for (int r = 0; r < 4; ++r) {
                int row = orow0 + mi * 16 + r;
                int col = ocol0 + ni * 16;
                O[(size_t)row * OUT_F + col] = acc[mi][ni][r] + bv[ni];
            }
}

extern "C" void kernel_launch(void* const* d_in, const int* in_sizes, int n_in,
                              void* d_out, int out_size, void* d_ws, size_t ws_size,
                              hipStream_t stream) {
    const float* X  = (const float*)d_in[0];
    const int*   QW = (const int*)d_in[1];
    const int*   QZ = (const int*)d_in[2];
    const float* S  = (const float*)d_in[3];
    const float* Bi = (const float*)d_in[4];
    float*       O  = (float*)d_out;

    if (ws_size >= WS_FULL) {
        unsigned short* Xsw = (unsigned short*)d_ws;
        unsigned short* Wsw = (unsigned short*)((unsigned char*)d_ws + XSW_BYTES);
        x_convert_kernel<<<dim3(TOKENS * IN_F / 8 / 256), dim3(256), 0, stream>>>(X, Xsw);
        w_dequant_kernel<<<dim3((int)(((size_t)NTILES * NKT * 1024) / 256)), dim3(256),
                           0, stream>>>(QW, QZ, S, Wsw);
        awq_gemm_full_kernel<<<dim3(8 * NTILES), dim3(512), 0, stream>>>(
            Xsw, Wsw, Bi, O);
    } else if (ws_size >= XSW_BYTES) {
        unsigned short* Xsw = (unsigned short*)d_ws;
        x_convert_kernel<<<dim3(TOKENS * IN_F / 8 / 256), dim3(256), 0, stream>>>(X, Xsw);
        awq_gemm_reg_kernel<<<dim3(8 * NTILES), dim3(512), 0, stream>>>(
            Xsw, QW, QZ, S, Bi, O);
    } else {
        awq_gemm_fb_kernel<<<dim3(8 * NTILES), dim3(512), 0, stream>>>(X, QW, QZ, S, Bi, O);
    }
}

// Round 20
// 347.064 us; speedup vs baseline: 1.1852x; 1.1852x over previous
//
#include <hip/hip_runtime.h>
#include <hip/hip_bf16.h>
#include <stdint.h>

// AWQ GEMM: out[2048,11008](f32) = x[2048,4096](f32,f16-valued) @ dequant4(...) + bias
// Round 20: ALL-REGISTER GEMM — no LDS, no barriers, no staging VALU.
//  r19 showed: dequant-hoist removes VALU (8%) but LDS/barrier lockstep + drained
//  B-DMA left MfmaUtil at 23%. Every 238us variant shared the 8-wave barrier
//  lockstep. This round removes it entirely:
//  K1: X f32->f16 in MFMA-A-fragment order -> Xsw (r16 layout, verified).
//  K2: W dequant once -> Wsw in MFMA-B-fragment order (same verified math).
//  K3: both operands global->reg (1KB/wave coalesced per frag), depth-1 reg
//      prefetch (B issued first: always L2-cold, needs most cover), 32 MFMA/iter,
//      NO __syncthreads, NO LDS. Waves fully independent.
// Tiers: ws >= 107MB -> K1+K2+K3 ; ws >= 16MB -> r16 path ; else r12 fallback.

constexpr int TOKENS = 2048;
constexpr int IN_F   = 4096;
constexpr int OUT_F  = 11008;
constexpr int PCOLS  = OUT_F / 8;   // 1376
constexpr int BM = 256, BN = 128, BK = 64;
constexpr int NKT    = IN_F / BK;   // 64
constexpr int NTILES = OUT_F / BN;  // 86
constexpr int BBYTES = BN * BK * 2; // 16384
constexpr size_t XSW_BYTES = (size_t)TOKENS * IN_F * 2;          // 16,777,216
constexpr size_t WSW_BYTES = (size_t)IN_F * OUT_F * 2;           // 90,177,536
constexpr size_t WS_FULL   = XSW_BYTES + WSW_BYTES;              // 106,954,752

typedef _Float16 h2 __attribute__((ext_vector_type(2)));
typedef _Float16 h8 __attribute__((ext_vector_type(8)));
typedef float f32x4  __attribute__((ext_vector_type(4)));

__device__ __forceinline__ h2 pkh2(float a, float b) {
    return __builtin_bit_cast(h2, __builtin_amdgcn_cvt_pkrtz(a, b));
}
__device__ __forceinline__ unsigned int pk2(float a, float b) {
    return __builtin_bit_cast(unsigned int, __builtin_amdgcn_cvt_pkrtz(a, b));
}

__constant__ int SHC[8] = {0, 16, 4, 20, 8, 24, 12, 28}; // shift of logical nibble j

// ---------------- K1: convert X into A-fragment-ordered f16 ----------------
__global__ __launch_bounds__(256)
void x_convert_kernel(const float* __restrict__ X, unsigned short* __restrict__ Xsw)
{
    // g = ((((mt*64 + kt)*2 + ks)*4 + wm)*4 + mi)*64 + lane
    const int g    = blockIdx.x * 256 + threadIdx.x;   // 0 .. 2^20-1
    const int lane = g & 63;
    const int mi   = (g >> 6) & 3;
    const int wm   = (g >> 8) & 3;
    const int ks   = (g >> 10) & 1;
    const int kt   = (g >> 11) & 63;
    const int mt   = g >> 17;
    const int row  = mt * 256 + wm * 64 + mi * 16 + (lane & 15);
    const int kcol = kt * 64 + (ks * 4 + (lane >> 4)) * 8;
    const float* src = X + (size_t)row * IN_F + kcol;
    float4 v0 = *(const float4*)(src);
    float4 v1 = *(const float4*)(src + 4);
    uint4 u;
    u.x = pk2(v0.x, v0.y);
    u.y = pk2(v0.z, v0.w);
    u.z = pk2(v1.x, v1.y);
    u.w = pk2(v1.z, v1.w);
    *(uint4*)(Xsw + (size_t)g * 8) = u;
}

// ---------------- K2: dequant W once into B-fragment-ordered f16 ----------------
// chunk id = ((((nt*64 + kt)*2 + ks)*8 + f)*64 + lane, f = wn*4+ni (0..7)
// lane holds col = nt*128 + f*16 + (lane&15), k = kt*64 + (ks*4 + lane>>4)*8 .. +8
__global__ __launch_bounds__(256)
void w_dequant_kernel(const int*   __restrict__ QW,
                      const int*   __restrict__ QZ,
                      const float* __restrict__ S,
                      unsigned short* __restrict__ Wsw)
{
    const int id   = blockIdx.x * 256 + threadIdx.x;
    const int lane = id & 63;
    const int f    = (id >> 6) & 7;
    const int ks   = (id >> 9) & 1;
    const int kt   = (id >> 10) & 63;
    const int nt   = id >> 16;

    const int col  = nt * 128 + f * 16 + (lane & 15);
    const int k0   = kt * 64 + (ks * 4 + (lane >> 4)) * 8;
    const int pcol = col >> 3;
    const int jsh  = SHC[col & 7];
    const int g    = kt >> 1;                          // group (gs=128); k0 within group

    const unsigned int zraw = ((const unsigned int*)QZ)[(size_t)g * PCOLS + pcol];
    const float s = S[(size_t)g * OUT_F + col];
    const h2 spk = pkh2(s, s);
    const float zb = 1024.0f + (float)((zraw >> jsh) & 15u);
    const h2 zpk = pkh2(zb, zb);

    unsigned int q[8];
#pragma unroll
    for (int kk = 0; kk < 8; ++kk) {
        unsigned int raw = (unsigned int)QW[(size_t)(k0 + kk) * PCOLS + pcol];
        q[kk] = ((raw >> jsh) & 15u) | 0x6400u;        // f16 (1024+q), exact
    }
    uint4 u;
    unsigned int* up = (unsigned int*)&u;
#pragma unroll
    for (int p = 0; p < 4; ++p) {
        unsigned int pair = q[2 * p] | (q[2 * p + 1] << 16);
        h2 wv = (__builtin_bit_cast(h2, pair) - zpk) * spk;   // exact sub, 1 rounding
        up[p] = __builtin_bit_cast(unsigned int, wv);
    }
    *(uint4*)(Wsw + (size_t)id * 8) = u;
}

// ---------------- K3: all-register GEMM (no LDS, no barriers) ----------------
__global__ __launch_bounds__(512, 2)
void awq_gemm_allreg_kernel(const unsigned short* __restrict__ Xsw,
                            const unsigned short* __restrict__ Wsw,
                            const float* __restrict__ BIAS,
                            float*       __restrict__ O)
{
    const int t    = threadIdx.x;
    const int lane = t & 63;
    const int w    = t >> 6;      // 0..7
    const int wm   = w >> 1;      // 0..3 (row block of 64)
    const int wn   = w & 1;       // 0..1 (col block of 64)
    const int l15 = lane & 15, l45 = lane >> 4;

    // XCD mapping: XCD x (= bid&7) owns mtile x (A panel L2-pinned);
    // blocks with the same ntile land on all 8 XCDs simultaneously -> one L3 fetch of W.
    const int bid   = blockIdx.x;
    const int mtile = bid & 7;
    const int ntile = bid >> 3;
    const int m0 = mtile * BM;
    const int n0 = ntile * BN;

    const h8* Afrag = (const h8*)Xsw;
    const h8* Bfrag = (const h8*)Wsw;

    // a-frags: (mtile, kt, ks, wm, mi);  b-frags: (ntile, kt, ks, f = wn*4+ni)
    auto load_b = [&](h8 (&b)[2][4], int kt) {
#pragma unroll
        for (int ks = 0; ks < 2; ++ks) {
            const size_t base = ((((size_t)ntile * 64 + kt) * 2 + ks) * 8 + wn * 4);
#pragma unroll
            for (int ni = 0; ni < 4; ++ni)
                b[ks][ni] = Bfrag[(base + ni) * 64 + lane];
        }
    };
    auto load_a = [&](h8 (&a)[2][4], int kt) {
#pragma unroll
        for (int ks = 0; ks < 2; ++ks) {
            const size_t base = ((((size_t)mtile * 64 + kt) * 2 + ks) * 4 + wm) * 4;
#pragma unroll
            for (int mi = 0; mi < 4; ++mi)
                a[ks][mi] = Afrag[(base + mi) * 64 + lane];
        }
    };

    f32x4 acc[4][4];
#pragma unroll
    for (int mi = 0; mi < 4; ++mi)
#pragma unroll
        for (int ni = 0; ni < 4; ++ni)
            acc[mi][ni] = f32x4{0.f, 0.f, 0.f, 0.f};

    auto compute = [&](const h8 (&a)[2][4], const h8 (&b)[2][4]) {
#pragma unroll
        for (int ks = 0; ks < 2; ++ks)
#pragma unroll
            for (int mi = 0; mi < 4; ++mi)
#pragma unroll
                for (int ni = 0; ni < 4; ++ni)
                    acc[mi][ni] = __builtin_amdgcn_mfma_f32_16x16x32_f16(
                        a[ks][mi], b[ks][ni], acc[mi][ni], 0, 0, 0);
    };

    h8 aA[2][4], aB[2][4], bA[2][4], bB[2][4];

    // ---- prologue ----
    load_b(bA, 0);           // B first: L2-cold, needs most latency cover
    load_a(aA, 0);

    // ---- main loop: depth-1 prefetch, static even/odd reg-set alternation ----
    auto K_ITER = [&](int kt, h8 (&aC)[2][4], h8 (&bC)[2][4],
                              h8 (&aN)[2][4], h8 (&bN)[2][4]) {
        if (kt + 1 < NKT) {
            load_b(bN, kt + 1);                // issue-early, oldest in queue
            load_a(aN, kt + 1);
        }
        compute(aC, bC);                       // compiler waits on aC/bC only
    };

#pragma unroll 1
    for (int kt = 0; kt < NKT; kt += 2) {
        K_ITER(kt,     aA, bA, aB, bB);
        K_ITER(kt + 1, aB, bB, aA, bA);
    }

    // ---- epilogue: bias + f32 store (C/D: col=lane&15, row=(lane>>4)*4+reg) ----
    const int orow0 = m0 + wm * 64 + l45 * 4;
    const int ocol0 = n0 + wn * 64 + l15;
    float bv[4];
#pragma unroll
    for (int ni = 0; ni < 4; ++ni)
        bv[ni] = BIAS[ocol0 + ni * 16];
#pragma unroll
    for (int mi = 0; mi < 4; ++mi)
#pragma unroll
        for (int ni = 0; ni < 4; ++ni)
#pragma unroll
            for (int r = 0; r < 4; ++r) {
                int row = orow0 + mi * 16 + r;
                int col = ocol0 + ni * 16;
                O[(size_t)row * OUT_F + col] = acc[mi][ni][r] + bv[ni];
            }
}

// ---------------- mid tier: r16 kernel (A reg, in-loop dequant) ----------------
__global__ __launch_bounds__(512, 2)
void awq_gemm_reg_kernel(const unsigned short* __restrict__ Xsw,
                         const int*   __restrict__ QW,
                         const int*   __restrict__ QZ,
                         const float* __restrict__ S,
                         const float* __restrict__ BIAS,
                         float*       __restrict__ O)
{
    __shared__ alignas(16) unsigned char smem[2 * BBYTES];

    const int t    = threadIdx.x;
    const int lane = t & 63;
    const int w    = t >> 6;
    const int wm   = w >> 1;
    const int wn   = w & 1;
    const int l15 = lane & 15, l45 = lane >> 4, l7 = lane & 7, l3 = (lane >> 3) & 1;

    const int bid   = blockIdx.x;
    const int mtile = bid & 7;
    const int ntile = bid >> 3;
    const int m0 = mtile * BM;
    const int n0 = ntile * BN;
    const int P0 = n0 >> 3;

    const h8* Afrag = (const h8*)Xsw;
    auto load_afull = [&](h8 (&a)[2][4], int kt) {
#pragma unroll
        for (int ks = 0; ks < 2; ++ks) {
            const size_t base = ((((size_t)mtile * 64 + kt) * 2 + ks) * 4 + wm) * 4;
#pragma unroll
            for (int mi = 0; mi < 4; ++mi)
                a[ks][mi] = Afrag[(base + mi) * 64 + lane];
        }
    };

    const int pcol = t & 15;
    const int kd   = t >> 4;
    const int pc7  = pcol & 7;
    const int ob   = kd >> 2;
    const int sub  = (kd & 3) * 4;
    const int* qwb = QW + (size_t)(2 * kd) * PCOLS + P0 + pcol;
    const unsigned int* qzc = (const unsigned int*)QZ + P0 + pcol;
    const float* scol = S + n0 + pcol * 8;

    constexpr int SH[8]  = {0, 16, 4, 20, 8, 24, 12, 28};
    constexpr int JLO[4] = {0, 4, 1, 5};

    h2 spk[8], zpk[8];
    unsigned int zraw_n; float4 sv0, sv1;
    unsigned int raw0, raw1;

    auto load_group = [&](int g) {
        zraw_n = qzc[(size_t)g * PCOLS];
        sv0 = *(const float4*)(scol + (size_t)g * OUT_F);
        sv1 = *(const float4*)(scol + (size_t)g * OUT_F + 4);
    };
    auto compute_group = [&]() {
        const float sf[8] = {sv0.x, sv0.y, sv0.z, sv0.w, sv1.x, sv1.y, sv1.z, sv1.w};
#pragma unroll
        for (int j = 0; j < 8; ++j) {
            float zb = 1024.0f + (float)((zraw_n >> SH[j]) & 15u);
            spk[j] = pkh2(sf[j], sf[j]);
            zpk[j] = pkh2(zb, zb);
        }
    };
    auto load_raws = [&](int kt) {
        const size_t off = (size_t)kt * BK * PCOLS;
        raw0 = (unsigned int)qwb[off];
        raw1 = (unsigned int)qwb[off + PCOLS];
    };
    auto stage_B = [&](int buf) {
        unsigned char* bb = smem + buf * BBYTES;
#pragma unroll
        for (int b = 0; b < 4; ++b) {
            const int jl = JLO[b], jh = jl + 2;
            unsigned int d  = __builtin_amdgcn_perm(raw1, raw0,
                                 (unsigned int)(((4 + b) << 16) | b));
            unsigned int lo = (d & 0x000F000Fu) | 0x64006400u;
            unsigned int hi = ((d >> 4) & 0x000F000Fu) | 0x64006400u;
            h2 wl = (__builtin_bit_cast(h2, lo) - zpk[jl]) * spk[jl];
            h2 wh = (__builtin_bit_cast(h2, hi) - zpk[jh]) * spk[jh];
            const int nl = pcol * 8 + jl, nh = pcol * 8 + jh;
            *(unsigned int*)(bb + nl * 128 + ((ob ^ jl ^ pc7) * 16) + sub) =
                __builtin_bit_cast(unsigned int, wl);
            *(unsigned int*)(bb + nh * 128 + ((ob ^ jh ^ pc7) * 16) + sub) =
                __builtin_bit_cast(unsigned int, wh);
        }
    };

    f32x4 acc[4][4];
#pragma unroll
    for (int mi = 0; mi < 4; ++mi)
#pragma unroll
        for (int ni = 0; ni < 4; ++ni)
            acc[mi][ni] = f32x4{0.f, 0.f, 0.f, 0.f};

    auto compute_tile = [&](int buf, const h8 (&a)[2][4]) {
        const unsigned char* bb = smem + buf * BBYTES;
#pragma unroll
        for (int ks = 0; ks < 2; ++ks) {
            h8 bf[4];
#pragma unroll
            for (int ni = 0; ni < 4; ++ni) {
                int off = (wn * 64 + ni * 16 + l15) * 128
                        + ((((ks * 4 + l45) ^ l7 ^ l3) ^ (2 * ni)) * 16);
                bf[ni] = *(const h8*)(bb + off);
            }
#pragma unroll
            for (int mi = 0; mi < 4; ++mi)
#pragma unroll
                for (int ni = 0; ni < 4; ++ni)
                    acc[mi][ni] = __builtin_amdgcn_mfma_f32_16x16x32_f16(
                        a[ks][mi], bf[ni], acc[mi][ni], 0, 0, 0);
        }
    };

    h8 aA[2][4], aB[2][4];

    load_afull(aA, 0);
    load_raws(0);
    load_group(0);
    compute_group();
    stage_B(0);
    __syncthreads();

    auto K_ITER = [&](int kt, h8 (&aC)[2][4], h8 (&aN)[2][4]) {
        const int cur = kt & 1;
        if (kt + 1 < NKT) {
            load_afull(aN, kt + 1);
            load_raws(kt + 1);
            if (((kt + 1) & 1) == 0) load_group((kt + 1) >> 1);
        }
        compute_tile(cur, aC);
        if (kt + 1 < NKT) {
            if (((kt + 1) & 1) == 0) compute_group();
            stage_B(cur ^ 1);
        }
        __syncthreads();
    };

#pragma unroll 1
    for (int kt = 0; kt < NKT; kt += 2) {
        K_ITER(kt,     aA, aB);
        K_ITER(kt + 1, aB, aA);
    }

    const int orow0 = m0 + wm * 64 + l45 * 4;
    const int ocol0 = n0 + wn * 64 + l15;
    float bv[4];
#pragma unroll
    for (int ni = 0; ni < 4; ++ni)
        bv[ni] = BIAS[ocol0 + ni * 16];
#pragma unroll
    for (int mi = 0; mi < 4; ++mi)
#pragma unroll
        for (int ni = 0; ni < 4; ++ni)
#pragma unroll
            for (int r = 0; r < 4; ++r) {
                int row = orow0 + mi * 16 + r;
                int col = ocol0 + ni * 16;
                O[(size_t)row * OUT_F + col] = acc[mi][ni][r] + bv[ni];
            }
}

// ---------------- fallback: r12 kernel (no usable ws) ----------------
constexpr int ABYTES_FB = BM * BK * 2; // 32768

__global__ __launch_bounds__(512, 2)
void awq_gemm_fb_kernel(const float* __restrict__ X,
                        const int*   __restrict__ QW,
                        const int*   __restrict__ QZ,
                        const float* __restrict__ S,
                        const float* __restrict__ BIAS,
                        float*       __restrict__ O)
{
    __shared__ alignas(16) unsigned char smem[ABYTES_FB + 2 * BBYTES];

    const int t    = threadIdx.x;
    const int lane = t & 63;
    const int w    = t >> 6;
    const int wm   = w >> 1;
    const int wn   = w & 1;
    const int l15 = lane & 15, l45 = lane >> 4, l7 = lane & 7, l3 = (lane >> 3) & 1;

    const int bid   = blockIdx.x;
    const int mtile = bid & 7;
    const int ntile = bid >> 3;
    const int m0 = mtile * BM;
    const int n0 = ntile * BN;
    const int P0 = n0 >> 3;

    const int arow = t >> 3;
    const int aoct = t & 7;
    const int aphys = aoct ^ (arow & 7);
    const float* Xb = X + (size_t)(m0 + arow) * IN_F + aoct * 8;

    float4 areg[4][2];
    auto load_A = [&](int kt) {
#pragma unroll
        for (int i = 0; i < 4; ++i) {
            const float* p = Xb + (size_t)i * 64 * IN_F + kt * BK;
            areg[i][0] = *(const float4*)(p);
            areg[i][1] = *(const float4*)(p + 4);
        }
    };
    auto write_A = [&]() {
        unsigned char* ab = smem;
#pragma unroll
        for (int i = 0; i < 4; ++i) {
            uint4 v;
            v.x = pk2(areg[i][0].x, areg[i][0].y);
            v.y = pk2(areg[i][0].z, areg[i][0].w);
            v.z = pk2(areg[i][1].x, areg[i][1].y);
            v.w = pk2(areg[i][1].z, areg[i][1].w);
            *(uint4*)(ab + (i * 64 + arow) * 128 + aphys * 16) = v;
        }
    };

    const int pcol = t & 15;
    const int kd   = t >> 4;
    const int pc7  = pcol & 7;
    const int ob   = kd >> 2;
    const int sub  = (kd & 3) * 4;
    const int* qwb = QW + (size_t)(2 * kd) * PCOLS + P0 + pcol;
    const unsigned int* qzc = (const unsigned int*)QZ + P0 + pcol;
    const float* scol = S + n0 + pcol * 8;

    constexpr int SH[8]  = {0, 16, 4, 20, 8, 24, 12, 28};
    constexpr int JLO[4] = {0, 4, 1, 5};

    h2 spk[8], zpk[8];
    unsigned int zraw_n; float4 sv0, sv1;
    unsigned int raw0, raw1;

    auto load_group = [&](int g) {
        zraw_n = qzc[(size_t)g * PCOLS];
        sv0 = *(const float4*)(scol + (size_t)g * OUT_F);
        sv1 = *(const float4*)(scol + (size_t)g * OUT_F + 4);
    };
    auto compute_group = [&]() {
        const float sf[8] = {sv0.x, sv0.y, sv0.z, sv0.w, sv1.x, sv1.y, sv1.z, sv1.w};
#pragma unroll
        for (int j = 0; j < 8; ++j) {
            float zb = 1024.0f + (float)((zraw_n >> SH[j]) & 15u);
            spk[j] = pkh2(sf[j], sf[j]);
            zpk[j] = pkh2(zb, zb);
        }
    };
    auto load_raws = [&](int kt) {
        const size_t off = (size_t)kt * BK * PCOLS;
        raw0 = (unsigned int)qwb[off];
        raw1 = (unsigned int)qwb[off + PCOLS];
    };
    auto stage_B = [&](int buf) {
        unsigned char* bb = smem + ABYTES_FB + buf * BBYTES;
#pragma unroll
        for (int b = 0; b < 4; ++b) {
            const int jl = JLO[b], jh = jl + 2;
            unsigned int d  = __builtin_amdgcn_perm(raw1, raw0,
                                 (unsigned int)(((4 + b) << 16) | b));
            unsigned int lo = (d & 0x000F000Fu) | 0x64006400u;
            unsigned int hi = ((d >> 4) & 0x000F000Fu) | 0x64006400u;
            h2 wl = (__builtin_bit_cast(h2, lo) - zpk[jl]) * spk[jl];
            h2 wh = (__builtin_bit_cast(h2, hi) - zpk[jh]) * spk[jh];
            const int nl = pcol * 8 + jl, nh = pcol * 8 + jh;
            *(unsigned int*)(bb + nl * 128 + ((ob ^ jl ^ pc7) * 16) + sub) =
                __builtin_bit_cast(unsigned int, wl);
            *(unsigned int*)(bb + nh * 128 + ((ob ^ jh ^ pc7) * 16) + sub) =
                __builtin_bit_cast(unsigned int, wh);
        }
    };

    f32x4 acc[4][4];
#pragma unroll
    for (int mi = 0; mi < 4; ++mi)
#pragma unroll
        for (int ni = 0; ni < 4; ++ni)
            acc[mi][ni] = f32x4{0.f, 0.f, 0.f, 0.f};

    auto compute_tile = [&](int buf) {
        const unsigned char* ab = smem;
        const unsigned char* bb = smem + ABYTES_FB + buf * BBYTES;
#pragma unroll
        for (int ks = 0; ks < 2; ++ks) {
            h8 a[4], bf[4];
#pragma unroll
            for (int mi = 0; mi < 4; ++mi) {
                int off = (wm * 64 + mi * 16 + l15) * 128
                        + (((ks * 4 + l45) ^ l7) * 16);
                a[mi] = *(const h8*)(ab + off);
            }
#pragma unroll
            for (int ni = 0; ni < 4; ++ni) {
                int off = (wn * 64 + ni * 16 + l15) * 128
                        + ((((ks * 4 + l45) ^ l7 ^ l3) ^ (2 * ni)) * 16);
                bf[ni] = *(const h8*)(bb + off);
            }
#pragma unroll
            for (int mi = 0; mi < 4; ++mi)
#pragma unroll
                for (int ni = 0; ni < 4; ++ni)
                    acc[mi][ni] = __builtin_amdgcn_mfma_f32_16x16x32_f16(
                        a[mi], bf[ni], acc[mi][ni], 0, 0, 0);
        }
    };

    load_A(0);
    load_raws(0);
    load_group(0);
    compute_group();
    write_A();
    stage_B(0);
    __syncthreads();

#pragma unroll 2
    for (int kt = 0; kt < NKT; ++kt) {
        const int cur = kt & 1;
        if (kt + 1 < NKT) {
            load_A(kt + 1);
            load_raws(kt + 1);
            if (((kt + 1) & 1) == 0) load_group((kt + 1) >> 1);
        }
        compute_tile(cur);
        if (kt + 1 < NKT) {
            if (((kt + 1) & 1) == 0) compute_group();
            stage_B(cur ^ 1);
        }
        __syncthreads();
        if (kt + 1 < NKT) write_A();
        __syncthreads();
    }

    const int orow0 = m0 + wm * 64 + l45 * 4;
    const int ocol0 = n0 + wn * 64 + l15;
    float bv[4];
#pragma unroll
    for (int ni = 0; ni < 4; ++ni)
        bv[ni] = BIAS[ocol0 + ni * 16];
#pragma unroll
    for (int mi = 0; mi < 4; ++mi)
#pragma unroll
        for (int ni = 0; ni < 4; ++ni)
#pragma unroll
            for (int r = 0; r < 4; ++r) {
                int row = orow0 + mi * 16 + r;
                int col = ocol0 + ni * 16;
                O[(size_t)row * OUT_F + col] = acc[mi][ni][r] + bv[ni];
            }
}

extern "C" void kernel_launch(void* const* d_in, const int* in_sizes, int n_in,
                              void* d_out, int out_size, void* d_ws, size_t ws_size,
                              hipStream_t stream) {
    const float* X  = (const float*)d_in[0];
    const int*   QW = (const int*)d_in[1];
    const int*   QZ = (const int*)d_in[2];
    const float* S  = (const float*)d_in[3];
    const float* Bi = (const float*)d_in[4];
    float*       O  = (float*)d_out;

    if (ws_size >= WS_FULL) {
        unsigned short* Xsw = (unsigned short*)d_ws;
        unsigned short* Wsw = (unsigned short*)((unsigned char*)d_ws + XSW_BYTES);
        x_convert_kernel<<<dim3(TOKENS * IN_F / 8 / 256), dim3(256), 0, stream>>>(X, Xsw);
        w_dequant_kernel<<<dim3((int)((WSW_BYTES / 16) / 256)), dim3(256), 0, stream>>>(
            QW, QZ, S, Wsw);
        awq_gemm_allreg_kernel<<<dim3(8 * NTILES), dim3(512), 0, stream>>>(
            Xsw, Wsw, Bi, O);
    } else if (ws_size >= XSW_BYTES) {
        unsigned short* Xsw = (unsigned short*)d_ws;
        x_convert_kernel<<<dim3(TOKENS * IN_F / 8 / 256), dim3(256), 0, stream>>>(X, Xsw);
        awq_gemm_reg_kernel<<<dim3(8 * NTILES), dim3(512), 0, stream>>>(
            Xsw, QW, QZ, S, Bi, O);
    } else {
        awq_gemm_fb_kernel<<<dim3(8 * NTILES), dim3(512), 0, stream>>>(X, QW, QZ, S, Bi, O);
    }
}